// Round 4
// baseline (405.041 us; speedup 1.0000x reference)
//
#include <hip/hip_runtime.h>
#include <math.h>

#define BH 64
#define NN 8192
#define DD 64
#define MM 32

#define NROWS (BH*NN)            // 524288
#define NORMC 0.35355339059327379f   // 64^-0.25
#define RATIO 0.17677669529663689f   // 32^-0.5
#define EPSK  1e-4f
#define DIAGC 0.0625f                // 0.5 * 64^-0.5

#define CPB 16                   // chunks per batch in kv kernel
#define CHUNK 512                // rows per chunk
#define K12_BLOCKS (BH*CPB)      // 1024

__device__ __forceinline__ float wave_max(float v) {
  #pragma unroll
  for (int off = 32; off > 0; off >>= 1)
    v = fmaxf(v, __shfl_down(v, off, 64));
  return v;
}

// ---------------- K12: fused k-features + outer-product partials ------------
// E' = exp(dash - diag) needs NO global max (max |dash| ~ 16 -> exp fp32-safe).
// The global max is applied as a constant scale in k2b:
//   kv  = ratio * (e^{-gmax} * Sum E'v + eps * Sum v)
//   ksum= ratio * (e^{-gmax} * Sum E'  + eps * N)
// This kills the 64MB s-buffer write+read and two launches.
__global__ __launch_bounds__(256) void k12_kv(
    const float* __restrict__ k, const float* __restrict__ v,
    const float* __restrict__ proj,
    float* __restrict__ kvPart, float* __restrict__ ksPart,
    float* __restrict__ vsPart, float* __restrict__ partialMax)
{
  __shared__ float kpL[8][258][4];   // [m_blk][row][m_lo], padded: 33 KB
  __shared__ float wmaxL[4];
  const int t = threadIdx.x;
  const int blk = blockIdx.x;
  const size_t base = (size_t)blk * CHUNK;   // NN = CPB*CHUNK -> rows contiguous

  const int dg = t & 7, mg = (t >> 3) & 7, ng = t >> 6;
  float acc[4][8];
  #pragma unroll
  for (int j = 0; j < 4; ++j)
    #pragma unroll
    for (int e = 0; e < 8; ++e) acc[j][e] = 0.f;
  float ksacc[4] = {0.f, 0.f, 0.f, 0.f};
  float vs[8] = {0.f,0.f,0.f,0.f,0.f,0.f,0.f,0.f};
  float tmax = -3.4e38f;

  for (int st = 0; st < CHUNK / 256; ++st) {
    const size_t rbase = base + st * 256;
    // ---- phase A: E' for 256 rows -> LDS (+ row max of dash)
    {
      const size_t row = rbase + t;
      const float4* kr = (const float4*)(k + row * DD);
      float4 kq[16];
      #pragma unroll
      for (int i = 0; i < 16; ++i) kq[i] = kr[i];
      float ssq = 0.f;
      #pragma unroll
      for (int i = 0; i < 16; ++i)
        ssq += kq[i].x*kq[i].x + kq[i].y*kq[i].y + kq[i].z*kq[i].z + kq[i].w*kq[i].w;
      const float diag = DIAGC * ssq;
      float p[MM];
      float rmax = -3.4e38f;
      #pragma unroll
      for (int m = 0; m < MM; ++m) {
        const float4* pm = (const float4*)(proj + m * DD);
        float a = 0.f;
        #pragma unroll
        for (int i = 0; i < 16; ++i) {
          float4 p4 = pm[i];
          a = fmaf(kq[i].x, p4.x, a);
          a = fmaf(kq[i].y, p4.y, a);
          a = fmaf(kq[i].z, p4.z, a);
          a = fmaf(kq[i].w, p4.w, a);
        }
        a *= NORMC;
        rmax = fmaxf(rmax, a);
        p[m] = __expf(a - diag);
      }
      tmax = fmaxf(tmax, rmax);
      #pragma unroll
      for (int mb = 0; mb < 8; ++mb) {
        kpL[mb][t][0] = p[4*mb];
        kpL[mb][t][1] = p[4*mb+1];
        kpL[mb][t][2] = p[4*mb+2];
        kpL[mb][t][3] = p[4*mb+3];
      }
    }
    __syncthreads();
    // ---- phase B: register-tiled outer-product accumulation (+ vsum)
    {
      #pragma unroll 4
      for (int i = 0; i < 64; ++i) {
        const int n = (ng << 6) + i;
        const float4 kp4 = *(const float4*)&kpL[mg][n][0];
        const float4* vr = (const float4*)(v + (rbase + n) * DD + dg * 8);
        const float4 va = vr[0], vb = vr[1];
        #pragma unroll
        for (int j = 0; j < 4; ++j) {
          const float pj = (&kp4.x)[j];
          acc[j][0] = fmaf(pj, va.x, acc[j][0]);
          acc[j][1] = fmaf(pj, va.y, acc[j][1]);
          acc[j][2] = fmaf(pj, va.z, acc[j][2]);
          acc[j][3] = fmaf(pj, va.w, acc[j][3]);
          acc[j][4] = fmaf(pj, vb.x, acc[j][4]);
          acc[j][5] = fmaf(pj, vb.y, acc[j][5]);
          acc[j][6] = fmaf(pj, vb.z, acc[j][6]);
          acc[j][7] = fmaf(pj, vb.w, acc[j][7]);
          ksacc[j] += pj;
        }
        vs[0] += va.x; vs[1] += va.y; vs[2] += va.z; vs[3] += va.w;
        vs[4] += vb.x; vs[5] += vb.y; vs[6] += vb.z; vs[7] += vb.w;
      }
    }
    __syncthreads();
  }

  // ---- block max of dash
  tmax = wave_max(tmax);
  if ((t & 63) == 0) wmaxL[t >> 6] = tmax;

  // ---- block reduction of kv over the 4 n-groups
  float* red = &kpL[0][0][0];   // 8256 floats of scratch
  #pragma unroll
  for (int j = 0; j < 4; ++j)
    #pragma unroll
    for (int e = 0; e < 8; ++e)
      red[t * 32 + j * 8 + e] = acc[j][e];
  __syncthreads();
  if (t == 0)
    partialMax[blk] = fmaxf(fmaxf(wmaxL[0], wmaxL[1]), fmaxf(wmaxL[2], wmaxL[3]));
  #pragma unroll
  for (int ii = 0; ii < 8; ++ii) {
    const int o = t + 256 * ii;
    const int m = o >> 6, d = o & 63;
    const int mg2 = m >> 2, j2 = m & 3, dg2 = d >> 3, e2 = d & 7;
    float s = 0.f;
    #pragma unroll
    for (int g = 0; g < 4; ++g)
      s += red[(dg2 + 8 * mg2 + 64 * g) * 32 + j2 * 8 + e2];
    kvPart[(size_t)blk * 2048 + o] = s;
  }
  __syncthreads();
  // ---- ksum partial
  if (dg == 0) {
    #pragma unroll
    for (int j = 0; j < 4; ++j)
      red[ng * 32 + mg * 4 + j] = ksacc[j];
  }
  __syncthreads();
  if (t < 32) {
    float s = red[t] + red[32 + t] + red[64 + t] + red[96 + t];
    ksPart[blk * 32 + t] = s;
  }
  __syncthreads();
  // ---- vsum partial (vs identical across mg; take mg==0 lanes)
  if (mg == 0) {
    #pragma unroll
    for (int j = 0; j < 8; ++j)
      red[ng * 64 + dg * 8 + j] = vs[j];
  }
  __syncthreads();
  if (t < 64)
    vsPart[blk * 64 + t] = red[t] + red[64 + t] + red[128 + t] + red[192 + t];
}

// ---------------- K2b: gmax + reduce partials -> kv, ksum -------------------
__global__ __launch_bounds__(256) void k2b_reduce(
    const float* __restrict__ kvPart, const float* __restrict__ ksPart,
    const float* __restrict__ vsPart, const float* __restrict__ partialMax,
    float* __restrict__ kvF, float* __restrict__ ksF)
{
  __shared__ float vsumL[64];
  __shared__ float wmaxL[4];
  __shared__ float gmaxL;
  const int b = blockIdx.x, t = threadIdx.x;
  // global max (every block computes it identically, fixed order)
  float mx = -3.4e38f;
  #pragma unroll
  for (int i = 0; i < 4; ++i) mx = fmaxf(mx, partialMax[t + 256 * i]);
  mx = wave_max(mx);
  if ((t & 63) == 0) wmaxL[t >> 6] = mx;
  // batch vsum
  if (t < 64) {
    float s = 0.f;
    for (int c = 0; c < CPB; ++c)
      s += vsPart[(b * CPB + c) * 64 + t];
    vsumL[t] = s;
  }
  __syncthreads();
  if (t == 0)
    gmaxL = fmaxf(fmaxf(wmaxL[0], wmaxL[1]), fmaxf(wmaxL[2], wmaxL[3]));
  __syncthreads();
  const float scale = __expf(-gmaxL);
  #pragma unroll
  for (int ii = 0; ii < 8; ++ii) {
    const int o = t + 256 * ii;
    float s = 0.f;
    for (int c = 0; c < CPB; ++c)
      s += kvPart[((size_t)(b * CPB + c)) * 2048 + o];
    kvF[b * 2048 + o] = RATIO * (scale * s + EPSK * vsumL[o & 63]);
  }
  if (t < 32) {
    float s = 0.f;
    for (int c = 0; c < CPB; ++c)
      s += ksPart[(b * CPB + c) * 32 + t];
    ksF[b * 32 + t] = RATIO * (scale * s + EPSK * (float)NN);
  }
}

// ---------------- K3: qp, num/den, output — 2 rows/thread -------------------
// Two independent FMA chains share every proj/kv scalar load: halves the
// s_load count per row and doubles the work available behind each stall.
__global__ __launch_bounds__(256, 3) void k3_out(
    const float* __restrict__ q, const float* __restrict__ proj,
    const float* __restrict__ kvF, const float* __restrict__ ksF,
    float* __restrict__ out)
{
  const int t = threadIdx.x;
  const int blk = blockIdx.x;               // 1024 blocks, 512 rows each
  const int b = blk >> 4;                   // 16 blocks per batch
  const size_t r0 = (size_t)blk * 512 + t;
  const size_t r1 = r0 + 256;
  const float* __restrict__ kvb = kvF + (size_t)b * 2048;
  const float* __restrict__ ksb = ksF + b * 32;
  const float4* qa = (const float4*)(q + r0 * DD);
  const float4* qb = (const float4*)(q + r1 * DD);
  const float4* pj = (const float4*)proj;

  float da[MM], db[MM];
  #pragma unroll
  for (int m = 0; m < MM; ++m) { da[m] = 0.f; db[m] = 0.f; }
  float ssqa = 0.f, ssqb = 0.f;

  #pragma unroll
  for (int h = 0; h < 2; ++h) {             // half-rows keep VGPRs bounded
    float4 A[8], B[8];
    #pragma unroll
    for (int i = 0; i < 8; ++i) { A[i] = qa[h*8+i]; B[i] = qb[h*8+i]; }
    #pragma unroll
    for (int i = 0; i < 8; ++i) {
      ssqa += A[i].x*A[i].x + A[i].y*A[i].y + A[i].z*A[i].z + A[i].w*A[i].w;
      ssqb += B[i].x*B[i].x + B[i].y*B[i].y + B[i].z*B[i].z + B[i].w*B[i].w;
    }
    #pragma unroll
    for (int m = 0; m < MM; ++m) {
      float sa = da[m], sb = db[m];
      #pragma unroll
      for (int i = 0; i < 8; ++i) {
        const float4 P = pj[m*16 + h*8 + i];
        sa = fmaf(A[i].x, P.x, sa); sb = fmaf(B[i].x, P.x, sb);
        sa = fmaf(A[i].y, P.y, sa); sb = fmaf(B[i].y, P.y, sb);
        sa = fmaf(A[i].z, P.z, sa); sb = fmaf(B[i].z, P.z, sb);
        sa = fmaf(A[i].w, P.w, sa); sb = fmaf(B[i].w, P.w, sb);
      }
      da[m] = sa; db[m] = sb;
    }
  }

  float mxa = -3.4e38f, mxb = -3.4e38f;
  #pragma unroll
  for (int m = 0; m < MM; ++m) {
    da[m] *= NORMC; mxa = fmaxf(mxa, da[m]);
    db[m] *= NORMC; mxb = fmaxf(mxb, db[m]);
  }
  const float suba = DIAGC * ssqa + mxa;
  const float subb = DIAGC * ssqb + mxb;
  #pragma unroll
  for (int m = 0; m < MM; ++m) {
    da[m] = RATIO * (__expf(da[m] - suba) + EPSK);
    db[m] = RATIO * (__expf(db[m] - subb) + EPSK);
  }
  float dena = 0.f, denb = 0.f;
  #pragma unroll
  for (int m = 0; m < MM; ++m) {
    dena = fmaf(da[m], ksb[m], dena);
    denb = fmaf(db[m], ksb[m], denb);
  }
  const float inva = 1.0f / dena;
  const float invb = 1.0f / denb;

  #pragma unroll
  for (int c = 0; c < 2; ++c) {
    float aa[32], ab[32];
    #pragma unroll
    for (int j = 0; j < 32; ++j) { aa[j] = 0.f; ab[j] = 0.f; }
    #pragma unroll
    for (int m = 0; m < MM; ++m) {
      const float* __restrict__ kr = kvb + m * 64 + c * 32;
      const float pa = da[m], pb = db[m];
      #pragma unroll
      for (int j = 0; j < 32; ++j) {
        const float kj = kr[j];            // wave-uniform -> s_load
        aa[j] = fmaf(pa, kj, aa[j]);
        ab[j] = fmaf(pb, kj, ab[j]);
      }
    }
    float4* oa = (float4*)(out + r0 * DD + c * 32);
    float4* ob = (float4*)(out + r1 * DD + c * 32);
    #pragma unroll
    for (int j4 = 0; j4 < 8; ++j4) {
      oa[j4] = make_float4(aa[4*j4]*inva, aa[4*j4+1]*inva,
                           aa[4*j4+2]*inva, aa[4*j4+3]*inva);
      ob[j4] = make_float4(ab[4*j4]*invb, ab[4*j4+1]*invb,
                           ab[4*j4+2]*invb, ab[4*j4+3]*invb);
    }
  }
}

// ---------------- host ------------------------------------------------------
extern "C" void kernel_launch(void* const* d_in, const int* in_sizes, int n_in,
                              void* d_out, int out_size, void* d_ws, size_t ws_size,
                              hipStream_t stream) {
  const float* q    = (const float*)d_in[0];
  const float* k    = (const float*)d_in[1];
  const float* v    = (const float*)d_in[2];
  const float* proj = (const float*)d_in[3];
  float* out = (float*)d_out;
  float* ws  = (float*)d_ws;

  float* partialMax = ws;                  // 1024 floats (pad to 2048)
  float* kvPart     = ws + 2048;           // 1024*2048
  float* ksPart     = kvPart + 2097152;    // 1024*32
  float* vsPart     = ksPart + 32768;      // 1024*64
  float* kvF        = vsPart + 65536;      // 64*2048
  float* ksF        = kvF + 131072;        // 64*32

  k12_kv<<<K12_BLOCKS, 256, 0, stream>>>(k, v, proj, kvPart, ksPart,
                                         vsPart, partialMax);
  k2b_reduce<<<BH, 256, 0, stream>>>(kvPart, ksPart, vsPart, partialMax,
                                     kvF, ksF);
  k3_out<<<NROWS / 512, 256, 0, stream>>>(q, proj, kvF, ksF, out);
}

// Round 5
// 368.788 us; speedup vs baseline: 1.0983x; 1.0983x over previous
//
#include <hip/hip_runtime.h>
#include <math.h>

#define BH 64
#define NN 8192
#define DD 64
#define MM 32

#define NROWS (BH*NN)            // 524288
#define NORMC 0.35355339059327379f   // 64^-0.25
#define RATIO 0.17677669529663689f   // 32^-0.5
#define EPSK  1e-4f
#define DIAGC 0.0625f                // 0.5 * 64^-0.5

#define CPB 16                   // chunks per batch in kv kernel
#define CHUNK 512                // rows per chunk
#define K2_BLOCKS (BH*CPB)       // 1024

__device__ __forceinline__ float wave_max(float v) {
  #pragma unroll
  for (int off = 32; off > 0; off >>= 1)
    v = fmaxf(v, __shfl_down(v, off, 64));
  return v;
}

// ---------------- K1: E' = exp(dash - diag), global-max partials, s-cache ----
// E' needs no global max (dash <= ~20 -> exp fp32-safe). gmax applied later
// as a constant scale in k2b:  kv = ratio*(e^{-gmax} Sum E'v + eps Sum v).
__global__ __launch_bounds__(256) void k1_dash_max(
    const float* __restrict__ k, const float* __restrict__ proj,
    float* __restrict__ partialMax, float* __restrict__ sOut)
{
  const int t = threadIdx.x;
  const size_t row = (size_t)blockIdx.x * 256 + t;
  const float4* kr = (const float4*)(k + row * DD);
  float4 kq[16];
  #pragma unroll
  for (int i = 0; i < 16; ++i) kq[i] = kr[i];
  float ssq = 0.f;
  #pragma unroll
  for (int i = 0; i < 16; ++i)
    ssq += kq[i].x*kq[i].x + kq[i].y*kq[i].y + kq[i].z*kq[i].z + kq[i].w*kq[i].w;
  const float diag = DIAGC * ssq;

  float ep[MM];
  float mx = -3.4e38f;
  #pragma unroll
  for (int m = 0; m < MM; ++m) {
    const float4* pm = (const float4*)(proj + m * DD);
    float a = 0.f;
    #pragma unroll
    for (int i = 0; i < 16; ++i) {
      float4 p4 = pm[i];
      a = fmaf(kq[i].x, p4.x, a);
      a = fmaf(kq[i].y, p4.y, a);
      a = fmaf(kq[i].z, p4.z, a);
      a = fmaf(kq[i].w, p4.w, a);
    }
    a *= NORMC;
    mx = fmaxf(mx, a);
    ep[m] = __expf(a - diag);
  }
  if (sOut) {
    float4* so = (float4*)(sOut + row * MM);
    #pragma unroll
    for (int j = 0; j < 8; ++j)
      so[j] = make_float4(ep[4*j], ep[4*j+1], ep[4*j+2], ep[4*j+3]);
  }
  mx = wave_max(mx);
  __shared__ float wmax[4];
  if ((t & 63) == 0) wmax[t >> 6] = mx;
  __syncthreads();
  if (t == 0)
    partialMax[blockIdx.x] = fmaxf(fmaxf(wmax[0], wmax[1]), fmaxf(wmax[2], wmax[3]));
}

// ---------------- K1b: reduce partial maxes -> global max -------------------
__global__ __launch_bounds__(256) void k1b_reduce_max(
    const float* __restrict__ partialMax, float* __restrict__ gmax)
{
  const int t = threadIdx.x;
  float mx = -3.4e38f;
  for (int i = t; i < 2048; i += 256) mx = fmaxf(mx, partialMax[i]);
  mx = wave_max(mx);
  __shared__ float wmax[4];
  if ((t & 63) == 0) wmax[t >> 6] = mx;
  __syncthreads();
  if (t == 0)
    *gmax = fmaxf(fmaxf(wmax[0], wmax[1]), fmaxf(wmax[2], wmax[3]));
}

// ---------------- K2: E' outer-product partials (+vsum) ---------------------
// Phase A is now a pure load (exp happened in k1); no gmax dependency at all.
template<bool USE_S>
__global__ __launch_bounds__(256) void k2_kv(
    const float* __restrict__ k, const float* __restrict__ v,
    const float* __restrict__ proj, const float* __restrict__ sBuf,
    float* __restrict__ kvPart, float* __restrict__ ksPart,
    float* __restrict__ vsPart)
{
  __shared__ float kpL[8][258][4];   // [m_blk][row][m_lo], padded: 33 KB
  const int t = threadIdx.x;
  const int b = blockIdx.x >> 4;
  const int c = blockIdx.x & (CPB - 1);
  const size_t base = (size_t)b * NN + (size_t)c * CHUNK;

  const int dg = t & 7, mg = (t >> 3) & 7, ng = t >> 6;
  float acc[4][8];
  #pragma unroll
  for (int j = 0; j < 4; ++j)
    #pragma unroll
    for (int e = 0; e < 8; ++e) acc[j][e] = 0.f;
  float ksacc[4] = {0.f, 0.f, 0.f, 0.f};
  float vs[8] = {0.f,0.f,0.f,0.f,0.f,0.f,0.f,0.f};

  for (int st = 0; st < CHUNK / 256; ++st) {
    const size_t rbase = base + st * 256;
    // ---- phase A: E' for 256 rows -> LDS
    {
      const size_t row = rbase + t;
      float p[MM];
      if (USE_S) {
        const float4* sr = (const float4*)(sBuf + row * MM);
        #pragma unroll
        for (int j = 0; j < 8; ++j) {
          float4 s4 = sr[j];
          p[4*j] = s4.x; p[4*j+1] = s4.y; p[4*j+2] = s4.z; p[4*j+3] = s4.w;
        }
      } else {
        const float4* kr = (const float4*)(k + row * DD);
        float4 kq[16];
        #pragma unroll
        for (int i = 0; i < 16; ++i) kq[i] = kr[i];
        float ssq = 0.f;
        #pragma unroll
        for (int i = 0; i < 16; ++i)
          ssq += kq[i].x*kq[i].x + kq[i].y*kq[i].y + kq[i].z*kq[i].z + kq[i].w*kq[i].w;
        const float diag = DIAGC * ssq;
        #pragma unroll
        for (int m = 0; m < MM; ++m) {
          const float4* pm = (const float4*)(proj + m * DD);
          float a = 0.f;
          #pragma unroll
          for (int i = 0; i < 16; ++i) {
            float4 p4 = pm[i];
            a = fmaf(kq[i].x, p4.x, a);
            a = fmaf(kq[i].y, p4.y, a);
            a = fmaf(kq[i].z, p4.z, a);
            a = fmaf(kq[i].w, p4.w, a);
          }
          p[m] = __expf(fmaf(a, NORMC, -diag));
        }
      }
      #pragma unroll
      for (int mb = 0; mb < 8; ++mb) {
        kpL[mb][t][0] = p[4*mb];
        kpL[mb][t][1] = p[4*mb+1];
        kpL[mb][t][2] = p[4*mb+2];
        kpL[mb][t][3] = p[4*mb+3];
      }
    }
    __syncthreads();
    // ---- phase B: register-tiled outer-product accumulation (+ vsum)
    {
      #pragma unroll 4
      for (int i = 0; i < 64; ++i) {
        const int n = (ng << 6) + i;
        const float4 kp4 = *(const float4*)&kpL[mg][n][0];
        const float4* vr = (const float4*)(v + (rbase + n) * DD + dg * 8);
        const float4 va = vr[0], vb = vr[1];
        #pragma unroll
        for (int j = 0; j < 4; ++j) {
          const float pj = (&kp4.x)[j];
          acc[j][0] = fmaf(pj, va.x, acc[j][0]);
          acc[j][1] = fmaf(pj, va.y, acc[j][1]);
          acc[j][2] = fmaf(pj, va.z, acc[j][2]);
          acc[j][3] = fmaf(pj, va.w, acc[j][3]);
          acc[j][4] = fmaf(pj, vb.x, acc[j][4]);
          acc[j][5] = fmaf(pj, vb.y, acc[j][5]);
          acc[j][6] = fmaf(pj, vb.z, acc[j][6]);
          acc[j][7] = fmaf(pj, vb.w, acc[j][7]);
          ksacc[j] += pj;
        }
        vs[0] += va.x; vs[1] += va.y; vs[2] += va.z; vs[3] += va.w;
        vs[4] += vb.x; vs[5] += vb.y; vs[6] += vb.z; vs[7] += vb.w;
      }
    }
    __syncthreads();
  }

  // ---- block reduction over the 4 n-groups
  float* red = &kpL[0][0][0];   // reuse LDS: need 8192 floats (have 8256)
  #pragma unroll
  for (int j = 0; j < 4; ++j)
    #pragma unroll
    for (int e = 0; e < 8; ++e)
      red[t * 32 + j * 8 + e] = acc[j][e];
  __syncthreads();
  #pragma unroll
  for (int ii = 0; ii < 8; ++ii) {
    const int o = t + 256 * ii;
    const int m = o >> 6, d = o & 63;
    const int mg2 = m >> 2, j2 = m & 3, dg2 = d >> 3, e2 = d & 7;
    float s = 0.f;
    #pragma unroll
    for (int g = 0; g < 4; ++g)
      s += red[(dg2 + 8 * mg2 + 64 * g) * 32 + j2 * 8 + e2];
    kvPart[(size_t)blockIdx.x * 2048 + o] = s;
  }
  __syncthreads();
  if (dg == 0) {
    #pragma unroll
    for (int j = 0; j < 4; ++j)
      red[ng * 32 + mg * 4 + j] = ksacc[j];
  }
  __syncthreads();
  if (t < 32) {
    float s = red[t] + red[32 + t] + red[64 + t] + red[96 + t];
    ksPart[blockIdx.x * 32 + t] = s;
  }
  __syncthreads();
  // vs identical across mg; take mg==0 lanes
  if (mg == 0) {
    #pragma unroll
    for (int j = 0; j < 8; ++j)
      red[ng * 64 + dg * 8 + j] = vs[j];
  }
  __syncthreads();
  if (t < 64)
    vsPart[blockIdx.x * 64 + t] = red[t] + red[64 + t] + red[128 + t] + red[192 + t];
}

// ---------------- K2b: fold gmax/eps + reduce partials -> kv, ksum ----------
__global__ __launch_bounds__(256) void k2b_reduce(
    const float* __restrict__ kvPart, const float* __restrict__ ksPart,
    const float* __restrict__ vsPart, const float* __restrict__ gmaxPtr,
    float* __restrict__ kvF, float* __restrict__ ksF)
{
  __shared__ float vsumL[64];
  const int b = blockIdx.x, t = threadIdx.x;
  const float scale = __expf(-*gmaxPtr);
  if (t < 64) {
    float s = 0.f;
    for (int c = 0; c < CPB; ++c)
      s += vsPart[(b * CPB + c) * 64 + t];
    vsumL[t] = s;
  }
  __syncthreads();
  #pragma unroll
  for (int ii = 0; ii < 8; ++ii) {
    const int o = t + 256 * ii;
    float s = 0.f;
    for (int c = 0; c < CPB; ++c)
      s += kvPart[((size_t)(b * CPB + c)) * 2048 + o];
    kvF[b * 2048 + o] = RATIO * (scale * s + EPSK * vsumL[o & 63]);
  }
  if (t < 32) {
    float s = 0.f;
    for (int c = 0; c < CPB; ++c)
      s += ksPart[(b * CPB + c) * 32 + t];
    ksF[b * 32 + t] = RATIO * (scale * s + EPSK * (float)NN);
  }
}

// ---------------- K3: qp, num/den, output -----------------------------------
// kv read through the VECTOR pipe (pointer pinned into a VGPR by the empty
// asm) -> global_load_dwordx4 from the L1-resident 8KB kv with deep vmcnt
// pipelining in VGPRs, instead of the SGPR-depth-limited s_load stream.
// 2 chunks of 32 cols -> full 128B store bursts (no partial-line writeback).
__global__ __launch_bounds__(256, 3) void k3_out(
    const float* __restrict__ q, const float* __restrict__ proj,
    const float* __restrict__ kvF, const float* __restrict__ ksF,
    float* __restrict__ out)
{
  const int t = threadIdx.x;
  const int b = blockIdx.x >> 5;              // 32 blocks of 256 rows per batch
  const size_t row = (size_t)blockIdx.x * 256 + t;
  const float* __restrict__ ksb = ksF + b * 32;

  unsigned long long kva = (unsigned long long)(kvF + (size_t)b * 2048);
  asm volatile("" : "+v"(kva));               // force VGPR addr -> vector loads
  const float* __restrict__ kvb = (const float*)kva;

  const float4* qr = (const float4*)(q + row * DD);
  float4 qq[16];
  #pragma unroll
  for (int i = 0; i < 16; ++i) qq[i] = qr[i];
  float ssq = 0.f;
  #pragma unroll
  for (int i = 0; i < 16; ++i)
    ssq += qq[i].x*qq[i].x + qq[i].y*qq[i].y + qq[i].z*qq[i].z + qq[i].w*qq[i].w;
  const float diag = DIAGC * ssq;

  float p[MM];
  float mx = -3.4e38f;
  #pragma unroll
  for (int m = 0; m < MM; ++m) {
    const float4* pm = (const float4*)(proj + m * DD);
    float a = 0.f;
    #pragma unroll
    for (int i = 0; i < 16; ++i) {
      float4 p4 = pm[i];
      a = fmaf(qq[i].x, p4.x, a);
      a = fmaf(qq[i].y, p4.y, a);
      a = fmaf(qq[i].z, p4.z, a);
      a = fmaf(qq[i].w, p4.w, a);
    }
    a *= NORMC;
    p[m] = a;
    mx = fmaxf(mx, a);
  }
  const float sub = diag + mx;
  #pragma unroll
  for (int m = 0; m < MM; ++m)
    p[m] = RATIO * (__expf(p[m] - sub) + EPSK);

  float den = 0.f;
  #pragma unroll
  for (int m = 0; m < MM; ++m)
    den = fmaf(p[m], ksb[m], den);
  const float inv = 1.0f / den;

  #pragma unroll
  for (int c = 0; c < 2; ++c) {
    float acc[32];
    #pragma unroll
    for (int j = 0; j < 32; ++j) acc[j] = 0.f;
    #pragma unroll
    for (int m = 0; m < MM; ++m) {
      const float pm = p[m];
      const float4* kr = (const float4*)(kvb + m * 64 + c * 32);
      #pragma unroll
      for (int j4 = 0; j4 < 8; ++j4) {
        const float4 k4 = kr[j4];     // same addr all lanes -> L1 broadcast
        acc[4*j4+0] = fmaf(pm, k4.x, acc[4*j4+0]);
        acc[4*j4+1] = fmaf(pm, k4.y, acc[4*j4+1]);
        acc[4*j4+2] = fmaf(pm, k4.z, acc[4*j4+2]);
        acc[4*j4+3] = fmaf(pm, k4.w, acc[4*j4+3]);
      }
    }
    float4* orow = (float4*)(out + row * DD + c * 32);
    #pragma unroll
    for (int j4 = 0; j4 < 8; ++j4)
      orow[j4] = make_float4(acc[4*j4]*inv, acc[4*j4+1]*inv,
                             acc[4*j4+2]*inv, acc[4*j4+3]*inv);
  }
}

// ---------------- host ------------------------------------------------------
extern "C" void kernel_launch(void* const* d_in, const int* in_sizes, int n_in,
                              void* d_out, int out_size, void* d_ws, size_t ws_size,
                              hipStream_t stream) {
  const float* q    = (const float*)d_in[0];
  const float* k    = (const float*)d_in[1];
  const float* v    = (const float*)d_in[2];
  const float* proj = (const float*)d_in[3];
  float* out = (float*)d_out;
  float* ws  = (float*)d_ws;

  float* partialMax = ws;                  // 2048 floats
  float* gmax       = ws + 2048;           // 1
  float* kvPart     = ws + 4096;           // 1024*2048
  float* ksPart     = kvPart + 2097152;    // 1024*32
  float* vsPart     = ksPart + 32768;      // 1024*64
  float* kvF        = vsPart + 65536;      // 64*2048
  float* ksF        = kvF + 131072;        // 64*32
  const size_t baseFloats = 4096 + 2097152 + 32768 + 65536 + 131072 + 2048;
  float* sBuf       = ws + baseFloats;     // 524288*32 floats (64 MB) if it fits
  const bool useS = ws_size >= (baseFloats + (size_t)NROWS * MM) * sizeof(float);

  k1_dash_max<<<NROWS / 256, 256, 0, stream>>>(k, proj, partialMax,
                                               useS ? sBuf : nullptr);
  k1b_reduce_max<<<1, 256, 0, stream>>>(partialMax, gmax);
  if (useS)
    k2_kv<true><<<K2_BLOCKS, 256, 0, stream>>>(k, v, proj, sBuf,
                                               kvPart, ksPart, vsPart);
  else
    k2_kv<false><<<K2_BLOCKS, 256, 0, stream>>>(k, v, proj, sBuf,
                                                kvPart, ksPart, vsPart);
  k2b_reduce<<<BH, 256, 0, stream>>>(kvPart, ksPart, vsPart, gmax, kvF, ksF);
  k3_out<<<NROWS / 256, 256, 0, stream>>>(q, proj, kvF, ksF, out);
}

// Round 6
// 260.044 us; speedup vs baseline: 1.5576x; 1.4182x over previous
//
#include <hip/hip_runtime.h>
#include <math.h>

#define BH 64
#define NN 8192
#define DD 64
#define MM 32

#define NROWS (BH*NN)            // 524288
#define NORMC 0.35355339059327379f   // 64^-0.25
#define RATIO 0.17677669529663689f   // 32^-0.5
#define EPSK  1e-4f
#define DIAGC 0.0625f                // 0.5 * 64^-0.5

#define CPB 16                   // chunks per batch in kv kernel
#define CHUNK 512                // rows per chunk
#define K2_BLOCKS (BH*CPB)       // 1024

__device__ __forceinline__ float wave_max(float v) {
  #pragma unroll
  for (int off = 32; off > 0; off >>= 1)
    v = fmaxf(v, __shfl_down(v, off, 64));
  return v;
}

// ---------------- K1: E' = exp(dash - diag), global-max partials, s-cache ----
// E' needs no global max (dash <= ~20 -> exp fp32-safe). gmax applied later
// as a constant scale in k2b:  kv = ratio*(e^{-gmax} Sum E'v + eps Sum v).
__global__ __launch_bounds__(256) void k1_dash_max(
    const float* __restrict__ k, const float* __restrict__ proj,
    float* __restrict__ partialMax, float* __restrict__ sOut)
{
  const int t = threadIdx.x;
  const size_t row = (size_t)blockIdx.x * 256 + t;
  const float4* kr = (const float4*)(k + row * DD);
  float4 kq[16];
  #pragma unroll
  for (int i = 0; i < 16; ++i) kq[i] = kr[i];
  float ssq = 0.f;
  #pragma unroll
  for (int i = 0; i < 16; ++i)
    ssq += kq[i].x*kq[i].x + kq[i].y*kq[i].y + kq[i].z*kq[i].z + kq[i].w*kq[i].w;
  const float diag = DIAGC * ssq;

  float ep[MM];
  float mx = -3.4e38f;
  #pragma unroll
  for (int m = 0; m < MM; ++m) {
    const float4* pm = (const float4*)(proj + m * DD);
    float a = 0.f;
    #pragma unroll
    for (int i = 0; i < 16; ++i) {
      float4 p4 = pm[i];
      a = fmaf(kq[i].x, p4.x, a);
      a = fmaf(kq[i].y, p4.y, a);
      a = fmaf(kq[i].z, p4.z, a);
      a = fmaf(kq[i].w, p4.w, a);
    }
    a *= NORMC;
    mx = fmaxf(mx, a);
    ep[m] = __expf(a - diag);
  }
  if (sOut) {
    float4* so = (float4*)(sOut + row * MM);
    #pragma unroll
    for (int j = 0; j < 8; ++j)
      so[j] = make_float4(ep[4*j], ep[4*j+1], ep[4*j+2], ep[4*j+3]);
  }
  mx = wave_max(mx);
  __shared__ float wmax[4];
  if ((t & 63) == 0) wmax[t >> 6] = mx;
  __syncthreads();
  if (t == 0)
    partialMax[blockIdx.x] = fmaxf(fmaxf(wmax[0], wmax[1]), fmaxf(wmax[2], wmax[3]));
}

// ---------------- K1b: reduce partial maxes -> global max -------------------
__global__ __launch_bounds__(256) void k1b_reduce_max(
    const float* __restrict__ partialMax, float* __restrict__ gmax)
{
  const int t = threadIdx.x;
  float mx = -3.4e38f;
  for (int i = t; i < 2048; i += 256) mx = fmaxf(mx, partialMax[i]);
  mx = wave_max(mx);
  __shared__ float wmax[4];
  if ((t & 63) == 0) wmax[t >> 6] = mx;
  __syncthreads();
  if (t == 0)
    *gmax = fmaxf(fmaxf(wmax[0], wmax[1]), fmaxf(wmax[2], wmax[3]));
}

// ---------------- K2: E' outer-product partials (+vsum) ---------------------
template<bool USE_S>
__global__ __launch_bounds__(256) void k2_kv(
    const float* __restrict__ k, const float* __restrict__ v,
    const float* __restrict__ proj, const float* __restrict__ sBuf,
    float* __restrict__ kvPart, float* __restrict__ ksPart,
    float* __restrict__ vsPart)
{
  __shared__ float kpL[8][258][4];   // [m_blk][row][m_lo], padded: 33 KB
  const int t = threadIdx.x;
  const int b = blockIdx.x >> 4;
  const int c = blockIdx.x & (CPB - 1);
  const size_t base = (size_t)b * NN + (size_t)c * CHUNK;

  const int dg = t & 7, mg = (t >> 3) & 7, ng = t >> 6;
  float acc[4][8];
  #pragma unroll
  for (int j = 0; j < 4; ++j)
    #pragma unroll
    for (int e = 0; e < 8; ++e) acc[j][e] = 0.f;
  float ksacc[4] = {0.f, 0.f, 0.f, 0.f};
  float vs[8] = {0.f,0.f,0.f,0.f,0.f,0.f,0.f,0.f};

  for (int st = 0; st < CHUNK / 256; ++st) {
    const size_t rbase = base + st * 256;
    // ---- phase A: E' for 256 rows -> LDS
    {
      const size_t row = rbase + t;
      float p[MM];
      if (USE_S) {
        const float4* sr = (const float4*)(sBuf + row * MM);
        #pragma unroll
        for (int j = 0; j < 8; ++j) {
          float4 s4 = sr[j];
          p[4*j] = s4.x; p[4*j+1] = s4.y; p[4*j+2] = s4.z; p[4*j+3] = s4.w;
        }
      } else {
        const float4* kr = (const float4*)(k + row * DD);
        float4 kq[16];
        #pragma unroll
        for (int i = 0; i < 16; ++i) kq[i] = kr[i];
        float ssq = 0.f;
        #pragma unroll
        for (int i = 0; i < 16; ++i)
          ssq += kq[i].x*kq[i].x + kq[i].y*kq[i].y + kq[i].z*kq[i].z + kq[i].w*kq[i].w;
        const float diag = DIAGC * ssq;
        #pragma unroll
        for (int m = 0; m < MM; ++m) {
          const float4* pm = (const float4*)(proj + m * DD);
          float a = 0.f;
          #pragma unroll
          for (int i = 0; i < 16; ++i) {
            float4 p4 = pm[i];
            a = fmaf(kq[i].x, p4.x, a);
            a = fmaf(kq[i].y, p4.y, a);
            a = fmaf(kq[i].z, p4.z, a);
            a = fmaf(kq[i].w, p4.w, a);
          }
          p[m] = __expf(fmaf(a, NORMC, -diag));
        }
      }
      #pragma unroll
      for (int mb = 0; mb < 8; ++mb) {
        kpL[mb][t][0] = p[4*mb];
        kpL[mb][t][1] = p[4*mb+1];
        kpL[mb][t][2] = p[4*mb+2];
        kpL[mb][t][3] = p[4*mb+3];
      }
    }
    __syncthreads();
    // ---- phase B: register-tiled outer-product accumulation (+ vsum)
    {
      #pragma unroll 4
      for (int i = 0; i < 64; ++i) {
        const int n = (ng << 6) + i;
        const float4 kp4 = *(const float4*)&kpL[mg][n][0];
        const float4* vr = (const float4*)(v + (rbase + n) * DD + dg * 8);
        const float4 va = vr[0], vb = vr[1];
        #pragma unroll
        for (int j = 0; j < 4; ++j) {
          const float pj = (&kp4.x)[j];
          acc[j][0] = fmaf(pj, va.x, acc[j][0]);
          acc[j][1] = fmaf(pj, va.y, acc[j][1]);
          acc[j][2] = fmaf(pj, va.z, acc[j][2]);
          acc[j][3] = fmaf(pj, va.w, acc[j][3]);
          acc[j][4] = fmaf(pj, vb.x, acc[j][4]);
          acc[j][5] = fmaf(pj, vb.y, acc[j][5]);
          acc[j][6] = fmaf(pj, vb.z, acc[j][6]);
          acc[j][7] = fmaf(pj, vb.w, acc[j][7]);
          ksacc[j] += pj;
        }
        vs[0] += va.x; vs[1] += va.y; vs[2] += va.z; vs[3] += va.w;
        vs[4] += vb.x; vs[5] += vb.y; vs[6] += vb.z; vs[7] += vb.w;
      }
    }
    __syncthreads();
  }

  // ---- block reduction over the 4 n-groups
  float* red = &kpL[0][0][0];   // reuse LDS: need 8192 floats (have 8256)
  #pragma unroll
  for (int j = 0; j < 4; ++j)
    #pragma unroll
    for (int e = 0; e < 8; ++e)
      red[t * 32 + j * 8 + e] = acc[j][e];
  __syncthreads();
  #pragma unroll
  for (int ii = 0; ii < 8; ++ii) {
    const int o = t + 256 * ii;
    const int m = o >> 6, d = o & 63;
    const int mg2 = m >> 2, j2 = m & 3, dg2 = d >> 3, e2 = d & 7;
    float s = 0.f;
    #pragma unroll
    for (int g = 0; g < 4; ++g)
      s += red[(dg2 + 8 * mg2 + 64 * g) * 32 + j2 * 8 + e2];
    kvPart[(size_t)blockIdx.x * 2048 + o] = s;
  }
  __syncthreads();
  if (dg == 0) {
    #pragma unroll
    for (int j = 0; j < 4; ++j)
      red[ng * 32 + mg * 4 + j] = ksacc[j];
  }
  __syncthreads();
  if (t < 32) {
    float s = red[t] + red[32 + t] + red[64 + t] + red[96 + t];
    ksPart[blockIdx.x * 32 + t] = s;
  }
  __syncthreads();
  if (mg == 0) {
    #pragma unroll
    for (int j = 0; j < 8; ++j)
      red[ng * 64 + dg * 8 + j] = vs[j];
  }
  __syncthreads();
  if (t < 64)
    vsPart[blockIdx.x * 64 + t] = red[t] + red[64 + t] + red[128 + t] + red[192 + t];
}

// ---------------- K2b: fold gmax/eps + reduce partials -> kv, ksum ----------
__global__ __launch_bounds__(256) void k2b_reduce(
    const float* __restrict__ kvPart, const float* __restrict__ ksPart,
    const float* __restrict__ vsPart, const float* __restrict__ gmaxPtr,
    float* __restrict__ kvF, float* __restrict__ ksF)
{
  __shared__ float vsumL[64];
  const int b = blockIdx.x, t = threadIdx.x;
  const float scale = __expf(-*gmaxPtr);
  if (t < 64) {
    float s = 0.f;
    for (int c = 0; c < CPB; ++c)
      s += vsPart[(b * CPB + c) * 64 + t];
    vsumL[t] = s;
  }
  __syncthreads();
  #pragma unroll
  for (int ii = 0; ii < 8; ++ii) {
    const int o = t + 256 * ii;
    float s = 0.f;
    for (int c = 0; c < CPB; ++c)
      s += kvPart[((size_t)(b * CPB + c)) * 2048 + o];
    kvF[b * 2048 + o] = RATIO * (scale * s + EPSK * vsumL[o & 63]);
  }
  if (t < 32) {
    float s = 0.f;
    for (int c = 0; c < CPB; ++c)
      s += ksPart[(b * CPB + c) * 32 + t];
    ksF[b * 32 + t] = RATIO * (scale * s + EPSK * (float)NN);
  }
}

// ---------------- K3: qp (per-row) -> pL, then TILED num --------------------
// Phase A: R2's proven per-row code; p scaled by 1/den before the pL write so
// phase B's accumulator IS the output (no inv redistribution).
// Phase B tiling: rg=t&63 owns 4 rows, cg=t>>6 (readfirstlane -> SGPR) owns a
// 16-col slice. Per m: one ds_read_b128 of p (64 lanes x 16B = balanced 8
// bank-cycles, conflict-free) + 16 uniform kv floats (s_load) + 64 FMA.
// Shared-operand instr pressure per wave: 32 ds + 128 s_load vs R2's 512
// s_load -> SMEM latency no longer on the critical path.
__global__ __launch_bounds__(256) void k3_out(
    const float* __restrict__ q, const float* __restrict__ proj,
    const float* __restrict__ kvF, const float* __restrict__ ksF,
    float* __restrict__ out)
{
  __shared__ float pL[MM][256];    // [m][row] p*inv, 32 KB
  const int t = threadIdx.x;
  const int b = blockIdx.x >> 5;              // 32 blocks of 256 rows per batch
  const size_t row = (size_t)blockIdx.x * 256 + t;
  const float* __restrict__ ksb = ksF + b * 32;

  // ---- phase A: per-row features
  {
    const float4* qr = (const float4*)(q + row * DD);
    float4 qq[16];
    #pragma unroll
    for (int i = 0; i < 16; ++i) qq[i] = qr[i];
    float ssq = 0.f;
    #pragma unroll
    for (int i = 0; i < 16; ++i)
      ssq += qq[i].x*qq[i].x + qq[i].y*qq[i].y + qq[i].z*qq[i].z + qq[i].w*qq[i].w;
    const float diag = DIAGC * ssq;

    float p[MM];
    float mx = -3.4e38f;
    #pragma unroll
    for (int m = 0; m < MM; ++m) {
      const float4* pm = (const float4*)(proj + m * DD);
      float a = 0.f;
      #pragma unroll
      for (int i = 0; i < 16; ++i) {
        float4 p4 = pm[i];
        a = fmaf(qq[i].x, p4.x, a);
        a = fmaf(qq[i].y, p4.y, a);
        a = fmaf(qq[i].z, p4.z, a);
        a = fmaf(qq[i].w, p4.w, a);
      }
      a *= NORMC;
      p[m] = a;
      mx = fmaxf(mx, a);
    }
    const float sub = diag + mx;
    #pragma unroll
    for (int m = 0; m < MM; ++m)
      p[m] = RATIO * (__expf(p[m] - sub) + EPSK);

    float den = 0.f;
    #pragma unroll
    for (int m = 0; m < MM; ++m)
      den = fmaf(p[m], ksb[m], den);
    const float inv = 1.0f / den;
    #pragma unroll
    for (int m = 0; m < MM; ++m)
      pL[m][t] = p[m] * inv;       // banks t%32: 2 lanes/bank, free
  }
  __syncthreads();

  // ---- phase B: tiled num GEMM, 4 rows x 16 cols per thread
  {
    const int rg = t & 63;
    const int cg = __builtin_amdgcn_readfirstlane(t >> 6);   // wave-uniform
    const float* __restrict__ kvc = kvF + (size_t)b * 2048 + cg * 16;

    float acc[64];
    #pragma unroll
    for (int j = 0; j < 64; ++j) acc[j] = 0.f;

    #pragma unroll
    for (int m = 0; m < MM; ++m) {
      const float4 pv = *(const float4*)&pL[m][rg << 2];
      const float* __restrict__ kr = kvc + m * 64;   // uniform -> s_load
      #pragma unroll
      for (int j = 0; j < 16; ++j) {
        const float kj = kr[j];
        acc[j]      = fmaf(pv.x, kj, acc[j]);
        acc[16 + j] = fmaf(pv.y, kj, acc[16 + j]);
        acc[32 + j] = fmaf(pv.z, kj, acc[32 + j]);
        acc[48 + j] = fmaf(pv.w, kj, acc[48 + j]);
      }
    }

    const size_t rowBase = (size_t)blockIdx.x * 256 + (rg << 2);
    #pragma unroll
    for (int r = 0; r < 4; ++r) {
      float4* o = (float4*)(out + (rowBase + r) * DD + cg * 16);
      o[0] = make_float4(acc[r*16+0],  acc[r*16+1],  acc[r*16+2],  acc[r*16+3]);
      o[1] = make_float4(acc[r*16+4],  acc[r*16+5],  acc[r*16+6],  acc[r*16+7]);
      o[2] = make_float4(acc[r*16+8],  acc[r*16+9],  acc[r*16+10], acc[r*16+11]);
      o[3] = make_float4(acc[r*16+12], acc[r*16+13], acc[r*16+14], acc[r*16+15]);
    }
  }
}

// ---------------- host ------------------------------------------------------
extern "C" void kernel_launch(void* const* d_in, const int* in_sizes, int n_in,
                              void* d_out, int out_size, void* d_ws, size_t ws_size,
                              hipStream_t stream) {
  const float* q    = (const float*)d_in[0];
  const float* k    = (const float*)d_in[1];
  const float* v    = (const float*)d_in[2];
  const float* proj = (const float*)d_in[3];
  float* out = (float*)d_out;
  float* ws  = (float*)d_ws;

  float* partialMax = ws;                  // 2048 floats
  float* gmax       = ws + 2048;           // 1
  float* kvPart     = ws + 4096;           // 1024*2048
  float* ksPart     = kvPart + 2097152;    // 1024*32
  float* vsPart     = ksPart + 32768;      // 1024*64
  float* kvF        = vsPart + 65536;      // 64*2048
  float* ksF        = kvF + 131072;        // 64*32
  const size_t baseFloats = 4096 + 2097152 + 32768 + 65536 + 131072 + 2048;
  float* sBuf       = ws + baseFloats;     // 524288*32 floats (64 MB) if it fits
  const bool useS = ws_size >= (baseFloats + (size_t)NROWS * MM) * sizeof(float);

  k1_dash_max<<<NROWS / 256, 256, 0, stream>>>(k, proj, partialMax,
                                               useS ? sBuf : nullptr);
  k1b_reduce_max<<<1, 256, 0, stream>>>(partialMax, gmax);
  if (useS)
    k2_kv<true><<<K2_BLOCKS, 256, 0, stream>>>(k, v, proj, sBuf,
                                               kvPart, ksPart, vsPart);
  else
    k2_kv<false><<<K2_BLOCKS, 256, 0, stream>>>(k, v, proj, sBuf,
                                                kvPart, ksPart, vsPart);
  k2b_reduce<<<BH, 256, 0, stream>>>(kvPart, ksPart, vsPart, gmax, kvF, ksF);
  k3_out<<<NROWS / 256, 256, 0, stream>>>(q, proj, kvF, ksF, out);
}

// Round 7
// 250.111 us; speedup vs baseline: 1.6194x; 1.0397x over previous
//
#include <hip/hip_runtime.h>
#include <math.h>

#define BH 64
#define NN 8192
#define DD 64
#define MM 32

#define NROWS (BH*NN)            // 524288
#define NORMC 0.35355339059327379f   // 64^-0.25
#define RATIO 0.17677669529663689f   // 32^-0.5
#define EPSK  1e-4f
#define DIAGC 0.0625f                // 0.5 * 64^-0.5

#define CPB 16                   // chunks per batch in kv kernel
#define CHUNK 512                // rows per chunk
#define K2_BLOCKS (BH*CPB)       // 1024

__device__ __forceinline__ float wave_max(float v) {
  #pragma unroll
  for (int off = 32; off > 0; off >>= 1)
    v = fmaxf(v, __shfl_down(v, off, 64));
  return v;
}

// ---------------- K1: E' = exp(dash - diag), global-max partials, s-cache ----
// Half-row (32-float) staging keeps natural live set ~75 VGPRs: dash[32] +
// 32 q floats; exp result reuses the dash registers.
__global__ __launch_bounds__(256) void k1_dash_max(
    const float* __restrict__ k, const float* __restrict__ proj,
    float* __restrict__ partialMax, float* __restrict__ sOut)
{
  const int t = threadIdx.x;
  const size_t row = (size_t)blockIdx.x * 256 + t;
  const float4* kr = (const float4*)(k + row * DD);
  const float4* pj = (const float4*)proj;

  float dash[MM];
  #pragma unroll
  for (int m = 0; m < MM; ++m) dash[m] = 0.f;
  float ssq = 0.f;

  #pragma unroll
  for (int h = 0; h < 2; ++h) {
    float4 A[8];
    #pragma unroll
    for (int i = 0; i < 8; ++i) A[i] = kr[h*8 + i];
    #pragma unroll
    for (int i = 0; i < 8; ++i)
      ssq += A[i].x*A[i].x + A[i].y*A[i].y + A[i].z*A[i].z + A[i].w*A[i].w;
    #pragma unroll
    for (int m = 0; m < MM; ++m) {
      float a = dash[m];
      #pragma unroll
      for (int i = 0; i < 8; ++i) {
        const float4 P = pj[m*16 + h*8 + i];
        a = fmaf(A[i].x, P.x, a);
        a = fmaf(A[i].y, P.y, a);
        a = fmaf(A[i].z, P.z, a);
        a = fmaf(A[i].w, P.w, a);
      }
      dash[m] = a;
    }
  }

  const float diag = DIAGC * ssq;
  float mx = -3.4e38f;
  #pragma unroll
  for (int m = 0; m < MM; ++m) {
    const float a = dash[m] * NORMC;
    mx = fmaxf(mx, a);
    dash[m] = __expf(a - diag);        // E', fp32-safe (a-diag <= ~20)
  }
  if (sOut) {
    float4* so = (float4*)(sOut + row * MM);
    #pragma unroll
    for (int j = 0; j < 8; ++j)
      so[j] = make_float4(dash[4*j], dash[4*j+1], dash[4*j+2], dash[4*j+3]);
  }
  mx = wave_max(mx);
  __shared__ float wmax[4];
  if ((t & 63) == 0) wmax[t >> 6] = mx;
  __syncthreads();
  if (t == 0)
    partialMax[blockIdx.x] = fmaxf(fmaxf(wmax[0], wmax[1]), fmaxf(wmax[2], wmax[3]));
}

// ---------------- K1b: reduce partial maxes -> global max -------------------
__global__ __launch_bounds__(256) void k1b_reduce_max(
    const float* __restrict__ partialMax, float* __restrict__ gmax)
{
  const int t = threadIdx.x;
  float mx = -3.4e38f;
  for (int i = t; i < 2048; i += 256) mx = fmaxf(mx, partialMax[i]);
  mx = wave_max(mx);
  __shared__ float wmax[4];
  if ((t & 63) == 0) wmax[t >> 6] = mx;
  __syncthreads();
  if (t == 0)
    *gmax = fmaxf(fmaxf(wmax[0], wmax[1]), fmaxf(wmax[2], wmax[3]));
}

// ---------------- K2: E' outer-product partials (+vsum) ---------------------
template<bool USE_S>
__global__ __launch_bounds__(256) void k2_kv(
    const float* __restrict__ k, const float* __restrict__ v,
    const float* __restrict__ proj, const float* __restrict__ sBuf,
    float* __restrict__ kvPart, float* __restrict__ ksPart,
    float* __restrict__ vsPart)
{
  __shared__ float kpL[8][258][4];   // [m_blk][row][m_lo], padded: 33 KB
  const int t = threadIdx.x;
  const int b = blockIdx.x >> 4;
  const int c = blockIdx.x & (CPB - 1);
  const size_t base = (size_t)b * NN + (size_t)c * CHUNK;

  const int dg = t & 7, mg = (t >> 3) & 7, ng = t >> 6;
  float acc[4][8];
  #pragma unroll
  for (int j = 0; j < 4; ++j)
    #pragma unroll
    for (int e = 0; e < 8; ++e) acc[j][e] = 0.f;
  float ksacc[4] = {0.f, 0.f, 0.f, 0.f};
  float vs[8] = {0.f,0.f,0.f,0.f,0.f,0.f,0.f,0.f};

  for (int st = 0; st < CHUNK / 256; ++st) {
    const size_t rbase = base + st * 256;
    // ---- phase A: E' for 256 rows -> LDS
    {
      const size_t row = rbase + t;
      float p[MM];
      if (USE_S) {
        const float4* sr = (const float4*)(sBuf + row * MM);
        #pragma unroll
        for (int j = 0; j < 8; ++j) {
          float4 s4 = sr[j];
          p[4*j] = s4.x; p[4*j+1] = s4.y; p[4*j+2] = s4.z; p[4*j+3] = s4.w;
        }
      } else {
        const float4* kr = (const float4*)(k + row * DD);
        float4 kq[16];
        #pragma unroll
        for (int i = 0; i < 16; ++i) kq[i] = kr[i];
        float ssq = 0.f;
        #pragma unroll
        for (int i = 0; i < 16; ++i)
          ssq += kq[i].x*kq[i].x + kq[i].y*kq[i].y + kq[i].z*kq[i].z + kq[i].w*kq[i].w;
        const float diag = DIAGC * ssq;
        #pragma unroll
        for (int m = 0; m < MM; ++m) {
          const float4* pm = (const float4*)(proj + m * DD);
          float a = 0.f;
          #pragma unroll
          for (int i = 0; i < 16; ++i) {
            float4 p4 = pm[i];
            a = fmaf(kq[i].x, p4.x, a);
            a = fmaf(kq[i].y, p4.y, a);
            a = fmaf(kq[i].z, p4.z, a);
            a = fmaf(kq[i].w, p4.w, a);
          }
          p[m] = __expf(fmaf(a, NORMC, -diag));
        }
      }
      #pragma unroll
      for (int mb = 0; mb < 8; ++mb) {
        kpL[mb][t][0] = p[4*mb];
        kpL[mb][t][1] = p[4*mb+1];
        kpL[mb][t][2] = p[4*mb+2];
        kpL[mb][t][3] = p[4*mb+3];
      }
    }
    __syncthreads();
    // ---- phase B: register-tiled outer-product accumulation (+ vsum)
    {
      #pragma unroll 4
      for (int i = 0; i < 64; ++i) {
        const int n = (ng << 6) + i;
        const float4 kp4 = *(const float4*)&kpL[mg][n][0];
        const float4* vr = (const float4*)(v + (rbase + n) * DD + dg * 8);
        const float4 va = vr[0], vb = vr[1];
        #pragma unroll
        for (int j = 0; j < 4; ++j) {
          const float pj = (&kp4.x)[j];
          acc[j][0] = fmaf(pj, va.x, acc[j][0]);
          acc[j][1] = fmaf(pj, va.y, acc[j][1]);
          acc[j][2] = fmaf(pj, va.z, acc[j][2]);
          acc[j][3] = fmaf(pj, va.w, acc[j][3]);
          acc[j][4] = fmaf(pj, vb.x, acc[j][4]);
          acc[j][5] = fmaf(pj, vb.y, acc[j][5]);
          acc[j][6] = fmaf(pj, vb.z, acc[j][6]);
          acc[j][7] = fmaf(pj, vb.w, acc[j][7]);
          ksacc[j] += pj;
        }
        vs[0] += va.x; vs[1] += va.y; vs[2] += va.z; vs[3] += va.w;
        vs[4] += vb.x; vs[5] += vb.y; vs[6] += vb.z; vs[7] += vb.w;
      }
    }
    __syncthreads();
  }

  // ---- block reduction over the 4 n-groups
  float* red = &kpL[0][0][0];   // reuse LDS: need 8192 floats (have 8256)
  #pragma unroll
  for (int j = 0; j < 4; ++j)
    #pragma unroll
    for (int e = 0; e < 8; ++e)
      red[t * 32 + j * 8 + e] = acc[j][e];
  __syncthreads();
  #pragma unroll
  for (int ii = 0; ii < 8; ++ii) {
    const int o = t + 256 * ii;
    const int m = o >> 6, d = o & 63;
    const int mg2 = m >> 2, j2 = m & 3, dg2 = d >> 3, e2 = d & 7;
    float s = 0.f;
    #pragma unroll
    for (int g = 0; g < 4; ++g)
      s += red[(dg2 + 8 * mg2 + 64 * g) * 32 + j2 * 8 + e2];
    kvPart[(size_t)blockIdx.x * 2048 + o] = s;
  }
  __syncthreads();
  if (dg == 0) {
    #pragma unroll
    for (int j = 0; j < 4; ++j)
      red[ng * 32 + mg * 4 + j] = ksacc[j];
  }
  __syncthreads();
  if (t < 32) {
    float s = red[t] + red[32 + t] + red[64 + t] + red[96 + t];
    ksPart[blockIdx.x * 32 + t] = s;
  }
  __syncthreads();
  if (mg == 0) {
    #pragma unroll
    for (int j = 0; j < 8; ++j)
      red[ng * 64 + dg * 8 + j] = vs[j];
  }
  __syncthreads();
  if (t < 64)
    vsPart[blockIdx.x * 64 + t] = red[t] + red[64 + t] + red[128 + t] + red[192 + t];
}

// ---------------- K2b: fold gmax/eps + reduce partials -> kv, ksum ----------
__global__ __launch_bounds__(256) void k2b_reduce(
    const float* __restrict__ kvPart, const float* __restrict__ ksPart,
    const float* __restrict__ vsPart, const float* __restrict__ gmaxPtr,
    float* __restrict__ kvF, float* __restrict__ ksF)
{
  __shared__ float vsumL[64];
  const int b = blockIdx.x, t = threadIdx.x;
  const float scale = __expf(-*gmaxPtr);
  if (t < 64) {
    float s = 0.f;
    for (int c = 0; c < CPB; ++c)
      s += vsPart[(b * CPB + c) * 64 + t];
    vsumL[t] = s;
  }
  __syncthreads();
  #pragma unroll
  for (int ii = 0; ii < 8; ++ii) {
    const int o = t + 256 * ii;
    float s = 0.f;
    for (int c = 0; c < CPB; ++c)
      s += kvPart[((size_t)(b * CPB + c)) * 2048 + o];
    kvF[b * 2048 + o] = RATIO * (scale * s + EPSK * vsumL[o & 63]);
  }
  if (t < 32) {
    float s = 0.f;
    for (int c = 0; c < CPB; ++c)
      s += ksPart[(b * CPB + c) * 32 + t];
    ksF[b * 32 + t] = RATIO * (scale * s + EPSK * (float)NN);
  }
}

// ---------------- K3: qp (per-row) -> pL, then TILED num --------------------
// launch_bounds(256,4): cap 128 VGPR / min 4 waves per SIMD -- stops the
// compiler's 60-VGPR reload restructure (LDS already caps at 5 blocks/CU, so
// extra occupancy beyond 4-5 waves buys nothing). Phase A processes q in two
// 32-float halves to keep natural pressure ~75; p reuses dash registers.
__global__ __launch_bounds__(256, 4) void k3_out(
    const float* __restrict__ q, const float* __restrict__ proj,
    const float* __restrict__ kvF, const float* __restrict__ ksF,
    float* __restrict__ out)
{
  __shared__ float pL[MM][256];    // [m][row] p*inv, 32 KB
  const int t = threadIdx.x;
  const int b = blockIdx.x >> 5;              // 32 blocks of 256 rows per batch
  const size_t row = (size_t)blockIdx.x * 256 + t;
  const float* __restrict__ ksb = ksF + b * 32;

  // ---- phase A: per-row features (half-row staging)
  {
    const float4* qr = (const float4*)(q + row * DD);
    const float4* pj = (const float4*)proj;
    float p[MM];
    #pragma unroll
    for (int m = 0; m < MM; ++m) p[m] = 0.f;
    float ssq = 0.f;

    #pragma unroll
    for (int h = 0; h < 2; ++h) {
      float4 A[8];
      #pragma unroll
      for (int i = 0; i < 8; ++i) A[i] = qr[h*8 + i];
      #pragma unroll
      for (int i = 0; i < 8; ++i)
        ssq += A[i].x*A[i].x + A[i].y*A[i].y + A[i].z*A[i].z + A[i].w*A[i].w;
      #pragma unroll
      for (int m = 0; m < MM; ++m) {
        float a = p[m];
        #pragma unroll
        for (int i = 0; i < 8; ++i) {
          const float4 P = pj[m*16 + h*8 + i];
          a = fmaf(A[i].x, P.x, a);
          a = fmaf(A[i].y, P.y, a);
          a = fmaf(A[i].z, P.z, a);
          a = fmaf(A[i].w, P.w, a);
        }
        p[m] = a;
      }
    }

    float mx = -3.4e38f;
    #pragma unroll
    for (int m = 0; m < MM; ++m) {
      p[m] *= NORMC;
      mx = fmaxf(mx, p[m]);
    }
    const float sub = DIAGC * ssq + mx;
    #pragma unroll
    for (int m = 0; m < MM; ++m)
      p[m] = RATIO * (__expf(p[m] - sub) + EPSK);

    float den = 0.f;
    #pragma unroll
    for (int m = 0; m < MM; ++m)
      den = fmaf(p[m], ksb[m], den);
    const float inv = 1.0f / den;
    #pragma unroll
    for (int m = 0; m < MM; ++m)
      pL[m][t] = p[m] * inv;       // banks t%32: 2 lanes/bank, free
  }
  __syncthreads();

  // ---- phase B: tiled num GEMM, 4 rows x 16 cols per thread
  {
    const int rg = t & 63;
    const int cg = __builtin_amdgcn_readfirstlane(t >> 6);   // wave-uniform
    const float4* __restrict__ kvc = (const float4*)(kvF + (size_t)b * 2048 + cg * 16);

    float acc[64];
    #pragma unroll
    for (int j = 0; j < 64; ++j) acc[j] = 0.f;

    #pragma unroll
    for (int m = 0; m < MM; ++m) {
      const float4 pv = *(const float4*)&pL[m][rg << 2];
      const float4 k0 = kvc[m*16 + 0];   // uniform -> s_load (64B/m)
      const float4 k1 = kvc[m*16 + 1];
      const float4 k2 = kvc[m*16 + 2];
      const float4 k3 = kvc[m*16 + 3];
      const float kj[16] = {k0.x,k0.y,k0.z,k0.w, k1.x,k1.y,k1.z,k1.w,
                            k2.x,k2.y,k2.z,k2.w, k3.x,k3.y,k3.z,k3.w};
      #pragma unroll
      for (int j = 0; j < 16; ++j) {
        acc[j]      = fmaf(pv.x, kj[j], acc[j]);
        acc[16 + j] = fmaf(pv.y, kj[j], acc[16 + j]);
        acc[32 + j] = fmaf(pv.z, kj[j], acc[32 + j]);
        acc[48 + j] = fmaf(pv.w, kj[j], acc[48 + j]);
      }
    }

    const size_t rowBase = (size_t)blockIdx.x * 256 + (rg << 2);
    #pragma unroll
    for (int r = 0; r < 4; ++r) {
      float4* o = (float4*)(out + (rowBase + r) * DD + cg * 16);
      o[0] = make_float4(acc[r*16+0],  acc[r*16+1],  acc[r*16+2],  acc[r*16+3]);
      o[1] = make_float4(acc[r*16+4],  acc[r*16+5],  acc[r*16+6],  acc[r*16+7]);
      o[2] = make_float4(acc[r*16+8],  acc[r*16+9],  acc[r*16+10], acc[r*16+11]);
      o[3] = make_float4(acc[r*16+12], acc[r*16+13], acc[r*16+14], acc[r*16+15]);
    }
  }
}

// ---------------- host ------------------------------------------------------
extern "C" void kernel_launch(void* const* d_in, const int* in_sizes, int n_in,
                              void* d_out, int out_size, void* d_ws, size_t ws_size,
                              hipStream_t stream) {
  const float* q    = (const float*)d_in[0];
  const float* k    = (const float*)d_in[1];
  const float* v    = (const float*)d_in[2];
  const float* proj = (const float*)d_in[3];
  float* out = (float*)d_out;
  float* ws  = (float*)d_ws;

  float* partialMax = ws;                  // 2048 floats
  float* gmax       = ws + 2048;           // 1
  float* kvPart     = ws + 4096;           // 1024*2048
  float* ksPart     = kvPart + 2097152;    // 1024*32
  float* vsPart     = ksPart + 32768;      // 1024*64
  float* kvF        = vsPart + 65536;      // 64*2048
  float* ksF        = kvF + 131072;        // 64*32
  const size_t baseFloats = 4096 + 2097152 + 32768 + 65536 + 131072 + 2048;
  float* sBuf       = ws + baseFloats;     // 524288*32 floats (64 MB) if it fits
  const bool useS = ws_size >= (baseFloats + (size_t)NROWS * MM) * sizeof(float);

  k1_dash_max<<<NROWS / 256, 256, 0, stream>>>(k, proj, partialMax,
                                               useS ? sBuf : nullptr);
  k1b_reduce_max<<<1, 256, 0, stream>>>(partialMax, gmax);
  if (useS)
    k2_kv<true><<<K2_BLOCKS, 256, 0, stream>>>(k, v, proj, sBuf,
                                               kvPart, ksPart, vsPart);
  else
    k2_kv<false><<<K2_BLOCKS, 256, 0, stream>>>(k, v, proj, sBuf,
                                                kvPart, ksPart, vsPart);
  k2b_reduce<<<BH, 256, 0, stream>>>(kvPart, ksPart, vsPart, gmax, kvF, ksF);
  k3_out<<<NROWS / 256, 256, 0, stream>>>(q, proj, kvF, ksF, out);
}

// Round 8
// 197.416 us; speedup vs baseline: 2.0517x; 1.2669x over previous
//
#include <hip/hip_runtime.h>
#include <math.h>

#define BH 64
#define NN 8192
#define DD 64
#define MM 32

#define NROWS (BH*NN)            // 524288
#define NORMC 0.35355339059327379f   // 64^-0.25
#define RATIO 0.17677669529663689f   // 32^-0.5
#define EPSK  1e-4f
#define DIAGC 0.0625f                // 0.5 * 64^-0.5

#define CPB 16                   // chunks per batch in kv kernel
#define CHUNK 512                // rows per chunk
#define K2_BLOCKS (BH*CPB)       // 1024

typedef __attribute__((ext_vector_type(8))) short short8;
typedef __attribute__((ext_vector_type(4))) float f32x4;

union FragU { uint4 u; short8 s; };

// round-to-nearest-even fp32 -> bf16 (bits in low 16)
__device__ __forceinline__ unsigned bf16r(float x) {
  unsigned u = __float_as_uint(x);
  return (u + 0x7fffu + ((u >> 16) & 1u)) >> 16;
}
// 8 fp32 -> hi/lo bf16x8 fragments (split: x = hi + lo)
__device__ __forceinline__ void cvt8(const float* f, FragU& hi, FragU& lo) {
  unsigned h[8], lw[8];
  #pragma unroll
  for (int j = 0; j < 8; ++j) {
    h[j] = bf16r(f[j]);
    lw[j] = bf16r(f[j] - __uint_as_float(h[j] << 16));
  }
  hi.u = make_uint4(h[0]|(h[1]<<16),  h[2]|(h[3]<<16),  h[4]|(h[5]<<16),  h[6]|(h[7]<<16));
  lo.u = make_uint4(lw[0]|(lw[1]<<16), lw[2]|(lw[3]<<16), lw[4]|(lw[5]<<16), lw[6]|(lw[7]<<16));
}

#define MFMA(a,b,c) __builtin_amdgcn_mfma_f32_16x16x32_bf16((a),(b),(c),0,0,0)

__device__ __forceinline__ float wave_max(float v) {
  #pragma unroll
  for (int off = 32; off > 0; off >>= 1)
    v = fmaxf(v, __shfl_down(v, off, 64));
  return v;
}

// ---------------- proj fragments: hi/lo bf16x8 per (mt,ks,lane) -------------
// B-frag (16x16x32): lane l holds B[k=(l>>4)*8+j][n=l&15]; B = proj^T so
// value = proj[mt*16 + (l&15)][ks*32 + (l>>4)*8 + j].
__global__ void kfrag_proj(const float* __restrict__ proj,
                           uint4* __restrict__ pfH, uint4* __restrict__ pfL)
{
  const int t = threadIdx.x;
  const int l = t & 63, g = t >> 6;          // g = mt*2 + ks
  const int mt = g >> 1, ks = g & 1;
  const int lr = l & 15, lg = l >> 4;
  float f[8];
  #pragma unroll
  for (int j = 0; j < 8; ++j)
    f[j] = proj[(mt*16 + lr)*DD + ks*32 + lg*8 + j];
  FragU hi, lo; cvt8(f, hi, lo);
  pfH[g*64 + l] = hi.u;
  pfL[g*64 + l] = lo.u;
}

// ---------------- K1: dash via MFMA, E' = exp(dash-diag) -> sBuf ------------
__global__ __launch_bounds__(256, 4) void k1_dash_max(
    const float* __restrict__ k,
    const uint4* __restrict__ pfH, const uint4* __restrict__ pfL,
    float* __restrict__ partialMax, float* __restrict__ sOut)
{
  __shared__ float dashL[256][36];
  __shared__ float ssqL[256][4];
  __shared__ float wmax[4];
  const int t = threadIdx.x;
  const int w = t >> 6, l = t & 63;
  const int lr = l & 15, lg = l >> 4;
  const size_t rowBase = (size_t)blockIdx.x * 256;
  const int wrb = w * 64;

  FragU pbH[2][2], pbL[2][2];
  #pragma unroll
  for (int mt = 0; mt < 2; ++mt)
    #pragma unroll
    for (int ks = 0; ks < 2; ++ks) {
      pbH[mt][ks].u = pfH[(mt*2+ks)*64 + l];
      pbL[mt][ks].u = pfL[(mt*2+ks)*64 + l];
    }

  // phase A: dash[wave-stripe 64 rows][32 m]
  #pragma unroll
  for (int rt = 0; rt < 4; ++rt) {
    const int rrow = wrb + rt*16 + lr;
    f32x4 acc0 = {0.f,0.f,0.f,0.f}, acc1 = {0.f,0.f,0.f,0.f};
    float sq = 0.f;
    #pragma unroll
    for (int ks = 0; ks < 2; ++ks) {
      const float4* src = (const float4*)(k + (rowBase + rrow)*DD + ks*32 + lg*8);
      float4 a0 = src[0], a1 = src[1];
      float qv[8] = {a0.x,a0.y,a0.z,a0.w, a1.x,a1.y,a1.z,a1.w};
      #pragma unroll
      for (int j = 0; j < 8; ++j) sq += qv[j]*qv[j];
      FragU aH, aL; cvt8(qv, aH, aL);
      acc0 = MFMA(aL.s, pbH[0][ks].s, acc0);
      acc0 = MFMA(aH.s, pbL[0][ks].s, acc0);
      acc0 = MFMA(aH.s, pbH[0][ks].s, acc0);
      acc1 = MFMA(aL.s, pbH[1][ks].s, acc1);
      acc1 = MFMA(aH.s, pbL[1][ks].s, acc1);
      acc1 = MFMA(aH.s, pbH[1][ks].s, acc1);
    }
    ssqL[rrow][lg] = sq;
    #pragma unroll
    for (int reg = 0; reg < 4; ++reg) {
      dashL[wrb + rt*16 + lg*4 + reg][lr]      = acc0[reg];
      dashL[wrb + rt*16 + lg*4 + reg][16 + lr] = acc1[reg];
    }
  }

  // SM-lite: row t (same wave as its stripe -> no barrier)
  float mx;
  {
    float dv[32];
    const float4* dr = (const float4*)&dashL[t][0];
    #pragma unroll
    for (int i = 0; i < 8; ++i) {
      float4 v4 = dr[i];
      dv[4*i]=v4.x; dv[4*i+1]=v4.y; dv[4*i+2]=v4.z; dv[4*i+3]=v4.w;
    }
    const float ssq = ssqL[t][0]+ssqL[t][1]+ssqL[t][2]+ssqL[t][3];
    const float diag = DIAGC * ssq;
    mx = -3.4e38f;
    #pragma unroll
    for (int m = 0; m < MM; ++m) { dv[m] *= NORMC; mx = fmaxf(mx, dv[m]); }
    #pragma unroll
    for (int m = 0; m < MM; ++m) dv[m] = __expf(dv[m] - diag);   // E'
    if (sOut) {
      float4* so = (float4*)(sOut + (rowBase + t) * MM);
      #pragma unroll
      for (int i = 0; i < 8; ++i)
        so[i] = make_float4(dv[4*i], dv[4*i+1], dv[4*i+2], dv[4*i+3]);
    }
  }
  mx = wave_max(mx);
  if (l == 0) wmax[w] = mx;
  __syncthreads();
  if (t == 0)
    partialMax[blockIdx.x] = fmaxf(fmaxf(wmax[0], wmax[1]), fmaxf(wmax[2], wmax[3]));
}

// ---------------- K1b: reduce partial maxes -> global max -------------------
__global__ __launch_bounds__(256) void k1b_reduce_max(
    const float* __restrict__ partialMax, float* __restrict__ gmax)
{
  const int t = threadIdx.x;
  float mx = -3.4e38f;
  for (int i = t; i < 2048; i += 256) mx = fmaxf(mx, partialMax[i]);
  mx = wave_max(mx);
  __shared__ float wmaxs[4];
  if ((t & 63) == 0) wmaxs[t >> 6] = mx;
  __syncthreads();
  if (t == 0)
    *gmax = fmaxf(fmaxf(wmaxs[0], wmaxs[1]), fmaxf(wmaxs[2], wmaxs[3]));
}

// ---------------- K2: E' outer-product partials (+vsum) — unchanged ---------
template<bool USE_S>
__global__ __launch_bounds__(256) void k2_kv(
    const float* __restrict__ k, const float* __restrict__ v,
    const float* __restrict__ proj, const float* __restrict__ sBuf,
    float* __restrict__ kvPart, float* __restrict__ ksPart,
    float* __restrict__ vsPart)
{
  __shared__ float kpL[8][258][4];
  const int t = threadIdx.x;
  const int b = blockIdx.x >> 4;
  const int c = blockIdx.x & (CPB - 1);
  const size_t base = (size_t)b * NN + (size_t)c * CHUNK;

  const int dg = t & 7, mg = (t >> 3) & 7, ng = t >> 6;
  float acc[4][8];
  #pragma unroll
  for (int j = 0; j < 4; ++j)
    #pragma unroll
    for (int e = 0; e < 8; ++e) acc[j][e] = 0.f;
  float ksacc[4] = {0.f, 0.f, 0.f, 0.f};
  float vs[8] = {0.f,0.f,0.f,0.f,0.f,0.f,0.f,0.f};

  for (int st = 0; st < CHUNK / 256; ++st) {
    const size_t rbase = base + st * 256;
    {
      const size_t row = rbase + t;
      float p[MM];
      if (USE_S) {
        const float4* sr = (const float4*)(sBuf + row * MM);
        #pragma unroll
        for (int j = 0; j < 8; ++j) {
          float4 s4 = sr[j];
          p[4*j] = s4.x; p[4*j+1] = s4.y; p[4*j+2] = s4.z; p[4*j+3] = s4.w;
        }
      } else {
        const float4* kr = (const float4*)(k + row * DD);
        float4 kq[16];
        #pragma unroll
        for (int i = 0; i < 16; ++i) kq[i] = kr[i];
        float ssq = 0.f;
        #pragma unroll
        for (int i = 0; i < 16; ++i)
          ssq += kq[i].x*kq[i].x + kq[i].y*kq[i].y + kq[i].z*kq[i].z + kq[i].w*kq[i].w;
        const float diag = DIAGC * ssq;
        #pragma unroll
        for (int m = 0; m < MM; ++m) {
          const float4* pm = (const float4*)(proj + m * DD);
          float a = 0.f;
          #pragma unroll
          for (int i = 0; i < 16; ++i) {
            float4 p4 = pm[i];
            a = fmaf(kq[i].x, p4.x, a);
            a = fmaf(kq[i].y, p4.y, a);
            a = fmaf(kq[i].z, p4.z, a);
            a = fmaf(kq[i].w, p4.w, a);
          }
          p[m] = __expf(fmaf(a, NORMC, -diag));
        }
      }
      #pragma unroll
      for (int mb = 0; mb < 8; ++mb) {
        kpL[mb][t][0] = p[4*mb];
        kpL[mb][t][1] = p[4*mb+1];
        kpL[mb][t][2] = p[4*mb+2];
        kpL[mb][t][3] = p[4*mb+3];
      }
    }
    __syncthreads();
    {
      #pragma unroll 4
      for (int i = 0; i < 64; ++i) {
        const int n = (ng << 6) + i;
        const float4 kp4 = *(const float4*)&kpL[mg][n][0];
        const float4* vr = (const float4*)(v + (rbase + n) * DD + dg * 8);
        const float4 va = vr[0], vb = vr[1];
        #pragma unroll
        for (int j = 0; j < 4; ++j) {
          const float pj = (&kp4.x)[j];
          acc[j][0] = fmaf(pj, va.x, acc[j][0]);
          acc[j][1] = fmaf(pj, va.y, acc[j][1]);
          acc[j][2] = fmaf(pj, va.z, acc[j][2]);
          acc[j][3] = fmaf(pj, va.w, acc[j][3]);
          acc[j][4] = fmaf(pj, vb.x, acc[j][4]);
          acc[j][5] = fmaf(pj, vb.y, acc[j][5]);
          acc[j][6] = fmaf(pj, vb.z, acc[j][6]);
          acc[j][7] = fmaf(pj, vb.w, acc[j][7]);
          ksacc[j] += pj;
        }
        vs[0] += va.x; vs[1] += va.y; vs[2] += va.z; vs[3] += va.w;
        vs[4] += vb.x; vs[5] += vb.y; vs[6] += vb.z; vs[7] += vb.w;
      }
    }
    __syncthreads();
  }

  float* red = &kpL[0][0][0];
  #pragma unroll
  for (int j = 0; j < 4; ++j)
    #pragma unroll
    for (int e = 0; e < 8; ++e)
      red[t * 32 + j * 8 + e] = acc[j][e];
  __syncthreads();
  #pragma unroll
  for (int ii = 0; ii < 8; ++ii) {
    const int o = t + 256 * ii;
    const int m = o >> 6, d = o & 63;
    const int mg2 = m >> 2, j2 = m & 3, dg2 = d >> 3, e2 = d & 7;
    float s = 0.f;
    #pragma unroll
    for (int g = 0; g < 4; ++g)
      s += red[(dg2 + 8 * mg2 + 64 * g) * 32 + j2 * 8 + e2];
    kvPart[(size_t)blockIdx.x * 2048 + o] = s;
  }
  __syncthreads();
  if (dg == 0) {
    #pragma unroll
    for (int j = 0; j < 4; ++j)
      red[ng * 32 + mg * 4 + j] = ksacc[j];
  }
  __syncthreads();
  if (t < 32) {
    float s = red[t] + red[32 + t] + red[64 + t] + red[96 + t];
    ksPart[blockIdx.x * 32 + t] = s;
  }
  __syncthreads();
  if (mg == 0) {
    #pragma unroll
    for (int j = 0; j < 8; ++j)
      red[ng * 64 + dg * 8 + j] = vs[j];
  }
  __syncthreads();
  if (t < 64)
    vsPart[blockIdx.x * 64 + t] = red[t] + red[64 + t] + red[128 + t] + red[192 + t];
}

// ---------------- K2b: reduce -> kv values (LDS) -> ksF + kv B-fragments ----
__global__ __launch_bounds__(256) void k2b_reduce(
    const float* __restrict__ kvPart, const float* __restrict__ ksPart,
    const float* __restrict__ vsPart, const float* __restrict__ gmaxPtr,
    float* __restrict__ ksF, uint4* __restrict__ kfH, uint4* __restrict__ kfL)
{
  __shared__ float vsumL[64];
  __shared__ float kvL[2048];
  const int b = blockIdx.x, t = threadIdx.x;
  const float scale = __expf(-*gmaxPtr);
  if (t < 64) {
    float s = 0.f;
    for (int c = 0; c < CPB; ++c)
      s += vsPart[(b * CPB + c) * 64 + t];
    vsumL[t] = s;
  }
  __syncthreads();
  #pragma unroll
  for (int ii = 0; ii < 8; ++ii) {
    const int o = t + 256 * ii;
    float s = 0.f;
    for (int c = 0; c < CPB; ++c)
      s += kvPart[((size_t)(b * CPB + c)) * 2048 + o];
    kvL[o] = RATIO * (scale * s + EPSK * vsumL[o & 63]);
  }
  if (t < 32) {
    float s = 0.f;
    for (int c = 0; c < CPB; ++c)
      s += ksPart[(b * CPB + c) * 32 + t];
    ksF[b * 32 + t] = RATIO * (scale * s + EPSK * (float)NN);
  }
  __syncthreads();
  // B-frag (16x16x32): lane l holds kv[k=(l>>4)*8+j][d = dt*16 + (l&15)]
  {
    const int l = t & 63, dt = t >> 6;
    const int lr = l & 15, lg = l >> 4;
    float f[8];
    #pragma unroll
    for (int j = 0; j < 8; ++j)
      f[j] = kvL[(lg*8 + j)*64 + dt*16 + lr];
    FragU hi, lo; cvt8(f, hi, lo);
    kfH[(b*4 + dt)*64 + l] = hi.u;
    kfL[(b*4 + dt)*64 + l] = lo.u;
  }
}

// ---------------- K3: dash MFMA -> softmax -> num MFMA (barrier-free) -------
__global__ __launch_bounds__(256, 4) void k3_out(
    const float* __restrict__ q,
    const uint4* __restrict__ pfH, const uint4* __restrict__ pfL,
    const uint4* __restrict__ kfH, const uint4* __restrict__ kfL,
    const float* __restrict__ ksF, float* __restrict__ out)
{
  __shared__ float dashL[256][36];   // fp32 dash; reused per-row as packed pstar
  __shared__ float ssqL[256][4];
  const int t = threadIdx.x;
  const int w = t >> 6, l = t & 63;
  const int lr = l & 15, lg = l >> 4;
  const int b = blockIdx.x >> 5;
  const size_t rowBase = (size_t)blockIdx.x * 256;
  const int wrb = w * 64;

  FragU pbH[2][2], pbL[2][2];
  #pragma unroll
  for (int mt = 0; mt < 2; ++mt)
    #pragma unroll
    for (int ks = 0; ks < 2; ++ks) {
      pbH[mt][ks].u = pfH[(mt*2+ks)*64 + l];
      pbL[mt][ks].u = pfL[(mt*2+ks)*64 + l];
    }

  // phase A
  #pragma unroll
  for (int rt = 0; rt < 4; ++rt) {
    const int rrow = wrb + rt*16 + lr;
    f32x4 acc0 = {0.f,0.f,0.f,0.f}, acc1 = {0.f,0.f,0.f,0.f};
    float sq = 0.f;
    #pragma unroll
    for (int ks = 0; ks < 2; ++ks) {
      const float4* src = (const float4*)(q + (rowBase + rrow)*DD + ks*32 + lg*8);
      float4 a0 = src[0], a1 = src[1];
      float qv[8] = {a0.x,a0.y,a0.z,a0.w, a1.x,a1.y,a1.z,a1.w};
      #pragma unroll
      for (int j = 0; j < 8; ++j) sq += qv[j]*qv[j];
      FragU aH, aL; cvt8(qv, aH, aL);
      acc0 = MFMA(aL.s, pbH[0][ks].s, acc0);
      acc0 = MFMA(aH.s, pbL[0][ks].s, acc0);
      acc0 = MFMA(aH.s, pbH[0][ks].s, acc0);
      acc1 = MFMA(aL.s, pbH[1][ks].s, acc1);
      acc1 = MFMA(aH.s, pbL[1][ks].s, acc1);
      acc1 = MFMA(aH.s, pbH[1][ks].s, acc1);
    }
    ssqL[rrow][lg] = sq;
    #pragma unroll
    for (int reg = 0; reg < 4; ++reg) {
      dashL[wrb + rt*16 + lg*4 + reg][lr]      = acc0[reg];
      dashL[wrb + rt*16 + lg*4 + reg][16 + lr] = acc1[reg];
    }
  }

  // softmax phase: thread t owns row t (same wave as its stripe: no barrier)
  {
    float dv[32];
    const float4* dr = (const float4*)&dashL[t][0];
    #pragma unroll
    for (int i = 0; i < 8; ++i) {
      float4 v4 = dr[i];
      dv[4*i]=v4.x; dv[4*i+1]=v4.y; dv[4*i+2]=v4.z; dv[4*i+3]=v4.w;
    }
    const float ssq = ssqL[t][0]+ssqL[t][1]+ssqL[t][2]+ssqL[t][3];
    float mx = -3.4e38f;
    #pragma unroll
    for (int m = 0; m < MM; ++m) { dv[m] *= NORMC; mx = fmaxf(mx, dv[m]); }
    const float sub = DIAGC * ssq + mx;
    const float* __restrict__ ksb = ksF + b * 32;
    float den = 0.f;
    #pragma unroll
    for (int m = 0; m < MM; ++m) {
      dv[m] = RATIO * (__expf(dv[m] - sub) + EPSK);
      den = fmaf(dv[m], ksb[m], den);
    }
    const float inv = 1.0f / den;
    unsigned hiw[16], low[16];
    #pragma unroll
    for (int u = 0; u < 16; ++u) {
      const float x0 = dv[2*u] * inv, x1 = dv[2*u+1] * inv;
      const unsigned h0 = bf16r(x0);
      const unsigned l0 = bf16r(x0 - __uint_as_float(h0 << 16));
      const unsigned h1 = bf16r(x1);
      const unsigned l1 = bf16r(x1 - __uint_as_float(h1 << 16));
      hiw[u] = h0 | (h1 << 16);
      low[u] = l0 | (l1 << 16);
    }
    uint4* pr = (uint4*)&dashL[t][0];   // overwrite own row only
    pr[0] = make_uint4(hiw[0],hiw[1],hiw[2],hiw[3]);
    pr[1] = make_uint4(hiw[4],hiw[5],hiw[6],hiw[7]);
    pr[2] = make_uint4(hiw[8],hiw[9],hiw[10],hiw[11]);
    pr[3] = make_uint4(hiw[12],hiw[13],hiw[14],hiw[15]);
    pr[4] = make_uint4(low[0],low[1],low[2],low[3]);
    pr[5] = make_uint4(low[4],low[5],low[6],low[7]);
    pr[6] = make_uint4(low[8],low[9],low[10],low[11]);
    pr[7] = make_uint4(low[12],low[13],low[14],low[15]);
  }

  // phase B: out = pstar · kv (K=32, one k-step, 3 comp terms)
  FragU kbH[4], kbL[4];
  #pragma unroll
  for (int dt = 0; dt < 4; ++dt) {
    kbH[dt].u = kfH[(b*4 + dt)*64 + l];
    kbL[dt].u = kfL[(b*4 + dt)*64 + l];
  }
  #pragma unroll
  for (int rt = 0; rt < 4; ++rt) {
    const uint4* pr = (const uint4*)&dashL[wrb + rt*16 + lr][0];
    FragU aH, aL;
    aH.u = pr[lg];
    aL.u = pr[4 + lg];
    #pragma unroll
    for (int dt = 0; dt < 4; ++dt) {
      f32x4 o = {0.f,0.f,0.f,0.f};
      o = MFMA(aL.s, kbH[dt].s, o);
      o = MFMA(aH.s, kbL[dt].s, o);
      o = MFMA(aH.s, kbH[dt].s, o);
      float* ob = out + (rowBase + wrb + rt*16 + lg*4)*DD + dt*16 + lr;
      ob[0]      = o[0];
      ob[DD]     = o[1];
      ob[2*DD]   = o[2];
      ob[3*DD]   = o[3];
    }
  }
}

// ---------------- host ------------------------------------------------------
extern "C" void kernel_launch(void* const* d_in, const int* in_sizes, int n_in,
                              void* d_out, int out_size, void* d_ws, size_t ws_size,
                              hipStream_t stream) {
  const float* q    = (const float*)d_in[0];
  const float* k    = (const float*)d_in[1];
  const float* v    = (const float*)d_in[2];
  const float* proj = (const float*)d_in[3];
  float* out = (float*)d_out;
  float* ws  = (float*)d_ws;

  float*    partialMax = ws;                       // 2048
  float*    gmax       = ws + 2048;                // (pad to 4096)
  float*    kvPart     = ws + 4096;                // 1024*2048
  float*    ksPart     = kvPart + 2097152;         // 1024*32
  float*    vsPart     = ksPart + 32768;           // 1024*64
  float*    ksF        = vsPart + 65536;           // 64*32 (pad 2048)
  unsigned* pfH        = (unsigned*)(ksF + 2048);  // 4*64 uint4 = 1024 words
  unsigned* pfL        = pfH + 1024;               // 1024
  unsigned* kfH        = pfL + 1024;               // 64*4*64 uint4 = 65536 words
  unsigned* kfL        = kfH + 65536;              // 65536
  float*    sBuf       = (float*)(kfL + 65536);    // 524288*32 floats (64 MB)
  const size_t baseFloats = 4096 + 2097152 + 32768 + 65536 + 2048
                          + 1024 + 1024 + 65536 + 65536;   // 2334720
  const bool useS = ws_size >= (baseFloats + (size_t)NROWS * MM) * sizeof(float);

  kfrag_proj<<<1, 256, 0, stream>>>(proj, (uint4*)pfH, (uint4*)pfL);
  k1_dash_max<<<NROWS / 256, 256, 0, stream>>>(k, (uint4*)pfH, (uint4*)pfL,
                                               partialMax, useS ? sBuf : nullptr);
  k1b_reduce_max<<<1, 256, 0, stream>>>(partialMax, gmax);
  if (useS)
    k2_kv<true><<<K2_BLOCKS, 256, 0, stream>>>(k, v, proj, sBuf,
                                               kvPart, ksPart, vsPart);
  else
    k2_kv<false><<<K2_BLOCKS, 256, 0, stream>>>(k, v, proj, sBuf,
                                                kvPart, ksPart, vsPart);
  k2b_reduce<<<BH, 256, 0, stream>>>(kvPart, ksPart, vsPart, gmax,
                                     ksF, (uint4*)kfH, (uint4*)kfL);
  k3_out<<<NROWS / 256, 256, 0, stream>>>(q, (uint4*)pfH, (uint4*)pfL,
                                          (uint4*)kfH, (uint4*)kfL, ksF, out);
}